// Round 1
// baseline (317.745 us; speedup 1.0000x reference)
//
#include <hip/hip_runtime.h>

#define BB 2048
#define CC 5
#define TT 2048
#define HH 16
#define OO 2

__device__ __forceinline__ float comp4(const float4& v, int j) {
    return j == 0 ? v.x : (j == 1 ? v.y : (j == 2 ? v.z : v.w));
}

__global__ __launch_bounds__(64) void snn_scan_kernel(
    const float* __restrict__ x,
    const float* __restrict__ conv_w,
    const float* __restrict__ conv_b,
    const float* __restrict__ bn_gamma,
    const float* __restrict__ bn_beta,
    const float* __restrict__ bn_mean,
    const float* __restrict__ bn_var,
    const float* __restrict__ fc_w,
    const float* __restrict__ fc_b,
    const float* __restrict__ beta1p,
    const float* __restrict__ beta2p,
    float* __restrict__ out)
{
    const int tid  = threadIdx.x;
    const int h    = tid & 15;        // hidden channel
    const int bsub = tid >> 4;        // batch element within wave (0..3)
    const int b    = blockIdx.x * 4 + bsub;

    // clip betas to [0,1]
    const float b1 = fminf(fmaxf(beta1p[0], 0.0f), 1.0f);
    const float b2 = fminf(fmaxf(beta2p[0], 0.0f), 1.0f);

    // fold conv mid-tap + BN:  feat[h] = sum_c x*effw + effb
    const float scale = bn_gamma[h] * rsqrtf(bn_var[h] + 1e-5f);
    float effw[CC];
#pragma unroll
    for (int c = 0; c < CC; ++c)
        effw[c] = 2.0f * conv_w[h * (CC * 3) + c * 3 + 1] * scale;
    const float effb = (conv_b[h] - bn_mean[h]) * scale + bn_beta[h];

    const float fw0 = fc_w[h];        // fc_w[0][h]
    const float fw1 = fc_w[HH + h];   // fc_w[1][h]
    const float fb0 = fc_b[0];
    const float fb1 = fc_b[1];

    const float* xb = x + (size_t)b * CC * TT;

    // scan state
    float mem1 = 0.0f, sub1 = 0.0f;               // per-lane h channel
    float mem2_0 = 0.0f, mem2_1 = 0.0f;           // redundant across 16 lanes
    float sub2_0 = 0.0f, sub2_1 = 0.0f;
    float acc0 = 0.0f, acc1 = 0.0f;

    // double-buffered x prefetch: 4 timesteps x 5 channels
    float4 cur[CC];
#pragma unroll
    for (int c = 0; c < CC; ++c)
        cur[c] = *reinterpret_cast<const float4*>(xb + c * TT);

#pragma unroll 1
    for (int t0 = 0; t0 < TT; t0 += 4) {
        const bool pf = (t0 + 4) < TT;
        float4 nxt[CC];
        if (pf) {
#pragma unroll
            for (int c = 0; c < CC; ++c)
                nxt[c] = *reinterpret_cast<const float4*>(xb + c * TT + t0 + 4);
        }

#pragma unroll
        for (int j = 0; j < 4; ++j) {
            // layer 1 current (conv mid-tap + BN folded)
            float feat = effb;
#pragma unroll
            for (int c = 0; c < CC; ++c)
                feat = fmaf(comp4(cur[c], j), effw[c], feat);

            // mem1 update: reset predicate == previous step's spike predicate
            mem1 = fmaf(b1, mem1, feat) - sub1;
            const bool s1 = mem1 > 1.0f;          // spk1 (and next reset1)
            sub1 = s1 ? 1.0f : 0.0f;
            float p0 = s1 ? fw0 : 0.0f;
            float p1 = s1 ? fw1 : 0.0f;

            // 16-lane butterfly reduce (stays within aligned 16-lane groups)
#pragma unroll
            for (int m = 1; m < 16; m <<= 1) {
                p0 += __shfl_xor(p0, m, 64);
                p1 += __shfl_xor(p1, m, 64);
            }
            const float cur2_0 = p0 + fb0;
            const float cur2_1 = p1 + fb1;

            // layer 2 (computed redundantly on all 16 lanes of the group)
            mem2_0 = fmaf(b2, mem2_0, cur2_0) - sub2_0;
            mem2_1 = fmaf(b2, mem2_1, cur2_1) - sub2_1;
            sub2_0 = (mem2_0 > 1.0f) ? 1.0f : 0.0f;
            sub2_1 = (mem2_1 > 1.0f) ? 1.0f : 0.0f;
            acc0 += sub2_0;                        // spk2 == sub2 value
            acc1 += sub2_1;
        }

        if (pf) {
#pragma unroll
            for (int c = 0; c < CC; ++c)
                cur[c] = nxt[c];
        }
    }

    if (h == 0) {
        out[(size_t)b * OO + 0] = acc0;
        out[(size_t)b * OO + 1] = acc1;
    }
}

extern "C" void kernel_launch(void* const* d_in, const int* in_sizes, int n_in,
                              void* d_out, int out_size, void* d_ws, size_t ws_size,
                              hipStream_t stream) {
    const float* x        = (const float*)d_in[0];
    const float* conv_w   = (const float*)d_in[1];
    const float* conv_b   = (const float*)d_in[2];
    const float* bn_gamma = (const float*)d_in[3];
    const float* bn_beta  = (const float*)d_in[4];
    const float* bn_mean  = (const float*)d_in[5];
    const float* bn_var   = (const float*)d_in[6];
    const float* fc_w     = (const float*)d_in[7];
    const float* fc_b     = (const float*)d_in[8];
    const float* beta1    = (const float*)d_in[9];
    const float* beta2    = (const float*)d_in[10];
    float* out = (float*)d_out;

    dim3 grid(BB / 4);
    dim3 block(64);
    snn_scan_kernel<<<grid, block, 0, stream>>>(
        x, conv_w, conv_b, bn_gamma, bn_beta, bn_mean, bn_var,
        fc_w, fc_b, beta1, beta2, out);
}

// Round 2
// 219.804 us; speedup vs baseline: 1.4456x; 1.4456x over previous
//
#include <hip/hip_runtime.h>

#define BB 2048
#define CC 5
#define TT 2048
#define HH 16
#define OO 2

__device__ __forceinline__ float comp4(const float4& v, int j) {
    return j == 0 ? v.x : (j == 1 ? v.y : (j == 2 ? v.z : v.w));
}

// DPP rotate-within-16-lane-row + add. row_ror:N ctrl = 0x120|N.
template<int CTRL>
__device__ __forceinline__ float dpp_ror_add(float v) {
    int s = __builtin_amdgcn_update_dpp(0, __float_as_int(v), CTRL, 0xf, 0xf, true);
    return v + __int_as_float(s);
}

// full 16-lane allreduce sum via rotation butterfly (stays in DPP row)
__device__ __forceinline__ float red16(float v) {
    v = dpp_ror_add<0x128>(v);  // ror 8
    v = dpp_ror_add<0x124>(v);  // ror 4
    v = dpp_ror_add<0x122>(v);  // ror 2
    v = dpp_ror_add<0x121>(v);  // ror 1
    return v;
}

__global__ __launch_bounds__(64) void snn_scan_kernel(
    const float* __restrict__ x,
    const float* __restrict__ conv_w,
    const float* __restrict__ conv_b,
    const float* __restrict__ bn_gamma,
    const float* __restrict__ bn_beta,
    const float* __restrict__ bn_mean,
    const float* __restrict__ bn_var,
    const float* __restrict__ fc_w,
    const float* __restrict__ fc_b,
    const float* __restrict__ beta1p,
    const float* __restrict__ beta2p,
    float* __restrict__ out)
{
    const int tid  = threadIdx.x;
    const int h    = tid & 15;        // hidden channel
    const int b    = blockIdx.x * 4 + (tid >> 4);

    const float b1 = fminf(fmaxf(beta1p[0], 0.0f), 1.0f);
    const float b2 = fminf(fmaxf(beta2p[0], 0.0f), 1.0f);

    // fold conv mid-tap + BN
    const float scale = bn_gamma[h] * rsqrtf(bn_var[h] + 1e-5f);
    float effw[CC];
#pragma unroll
    for (int c = 0; c < CC; ++c)
        effw[c] = 2.0f * conv_w[h * (CC * 3) + c * 3 + 1] * scale;
    const float effb = (conv_b[h] - bn_mean[h]) * scale + bn_beta[h];

    const float fw0 = fc_w[h];
    const float fw1 = fc_w[HH + h];
    const float fb0 = fc_b[0], fb0m = fb0 - 1.0f;
    const float fb1 = fc_b[1], fb1m = fb1 - 1.0f;

    const float* xb = x + (size_t)b * CC * TT;

    // scan state
    float mem1 = 0.0f, mem2_0 = 0.0f, mem2_1 = 0.0f;
    float acc0 = 0.0f, acc1 = 0.0f;
    bool s1 = false, s2_0 = false, s2_1 = false;

#define LD(c, t) (*reinterpret_cast<const float4*>(xb + (c) * TT + (t)))

    // 4-stage prefetch pipeline (16 steps ahead); all statically indexed
    float4 buf0[CC], buf1[CC], buf2[CC], buf3[CC];
#pragma unroll
    for (int c = 0; c < CC; ++c) {
        buf0[c] = LD(c, 0);
        buf1[c] = LD(c, 4);
        buf2[c] = LD(c, 8);
        buf3[c] = LD(c, 12);
    }

    auto step4 = [&](const float4 (&cur)[CC]) {
#pragma unroll
        for (int j = 0; j < 4; ++j) {
            // layer-1 current (off critical path: depends only on x)
            float feat = effb;
#pragma unroll
            for (int c = 0; c < CC; ++c)
                feat = fmaf(comp4(cur[c], j), effw[c], feat);
            const float featm = feat - 1.0f;

            // mem1 chain: cmp -> cndmask -> fma
            mem1 = fmaf(b1, mem1, s1 ? featm : feat);
            s1 = mem1 > 1.0f;

            // spike contributions, 16-lane DPP allreduce (pipelined vs mem1 chain)
            const float r0 = red16(s1 ? fw0 : 0.0f);
            const float r1 = red16(s1 ? fw1 : 0.0f);

            // layer-2: precompute both variants off-path, cndmask on-path
            const float q0 = r0 + fb0, q0m = r0 + fb0m;
            const float q1 = r1 + fb1, q1m = r1 + fb1m;

            mem2_0 = fmaf(b2, mem2_0, s2_0 ? q0m : q0);
            s2_0 = mem2_0 > 1.0f;
            acc0 += s2_0 ? 1.0f : 0.0f;

            mem2_1 = fmaf(b2, mem2_1, s2_1 ? q1m : q1);
            s2_1 = mem2_1 > 1.0f;
            acc1 += s2_1 ? 1.0f : 0.0f;
        }
    };

#pragma unroll 1
    for (int t0 = 0; t0 < TT; t0 += 16) {
        // clamped prefetch target (tail reloads same data harmlessly; uniform, branchless)
        const int tp = (t0 + 16 < TT) ? (t0 + 16) : t0;

        step4(buf0);
#pragma unroll
        for (int c = 0; c < CC; ++c) buf0[c] = LD(c, tp);
        step4(buf1);
#pragma unroll
        for (int c = 0; c < CC; ++c) buf1[c] = LD(c, tp + 4);
        step4(buf2);
#pragma unroll
        for (int c = 0; c < CC; ++c) buf2[c] = LD(c, tp + 8);
        step4(buf3);
#pragma unroll
        for (int c = 0; c < CC; ++c) buf3[c] = LD(c, tp + 12);
    }
#undef LD

    if (h == 0) {
        out[(size_t)b * OO + 0] = acc0;
        out[(size_t)b * OO + 1] = acc1;
    }
}

extern "C" void kernel_launch(void* const* d_in, const int* in_sizes, int n_in,
                              void* d_out, int out_size, void* d_ws, size_t ws_size,
                              hipStream_t stream) {
    const float* x        = (const float*)d_in[0];
    const float* conv_w   = (const float*)d_in[1];
    const float* conv_b   = (const float*)d_in[2];
    const float* bn_gamma = (const float*)d_in[3];
    const float* bn_beta  = (const float*)d_in[4];
    const float* bn_mean  = (const float*)d_in[5];
    const float* bn_var   = (const float*)d_in[6];
    const float* fc_w     = (const float*)d_in[7];
    const float* fc_b     = (const float*)d_in[8];
    const float* beta1    = (const float*)d_in[9];
    const float* beta2    = (const float*)d_in[10];
    float* out = (float*)d_out;

    dim3 grid(BB / 4);
    dim3 block(64);
    snn_scan_kernel<<<grid, block, 0, stream>>>(
        x, conv_w, conv_b, bn_gamma, bn_beta, bn_mean, bn_var,
        fc_w, fc_b, beta1, beta2, out);
}

// Round 3
// 116.758 us; speedup vs baseline: 2.7214x; 1.8826x over previous
//
#include <hip/hip_runtime.h>

#define BB 2048
#define CC 5
#define TT 2048
#define HH 16
#define OO 2

#define NCH  8            // T-chunks (speculative parallel scan)
#define CHT  (TT / NCH)   // 256 steps measured per chunk
#define WARM 128          // speculative warm-up steps (0.8^128 ~ 4e-13 << fp32 ulp)

__device__ __forceinline__ float comp4(const float4& v, int j) {
    return j == 0 ? v.x : (j == 1 ? v.y : (j == 2 ? v.z : v.w));
}

// DPP rotate-within-16-lane-row + add. row_ror:N ctrl = 0x120|N.
template<int CTRL>
__device__ __forceinline__ float dpp_ror_add(float v) {
    int s = __builtin_amdgcn_update_dpp(0, __float_as_int(v), CTRL, 0xf, 0xf, true);
    return v + __int_as_float(s);
}

// full 16-lane allreduce sum via rotation butterfly (stays in DPP row)
__device__ __forceinline__ float red16(float v) {
    v = dpp_ror_add<0x128>(v);  // ror 8
    v = dpp_ror_add<0x124>(v);  // ror 4
    v = dpp_ror_add<0x122>(v);  // ror 2
    v = dpp_ror_add<0x121>(v);  // ror 1
    return v;
}

__global__ __launch_bounds__(64) void snn_chunk_kernel(
    const float* __restrict__ x,
    const float* __restrict__ conv_w,
    const float* __restrict__ conv_b,
    const float* __restrict__ bn_gamma,
    const float* __restrict__ bn_beta,
    const float* __restrict__ bn_mean,
    const float* __restrict__ bn_var,
    const float* __restrict__ fc_w,
    const float* __restrict__ fc_b,
    const float* __restrict__ beta1p,
    const float* __restrict__ beta2p,
    float* __restrict__ out)
{
    const int tid   = threadIdx.x;
    const int h     = tid & 15;
    const int b     = blockIdx.x * 4 + (tid >> 4);
    const int chunk = blockIdx.y;

    const float b1 = fminf(fmaxf(beta1p[0], 0.0f), 1.0f);
    const float b2 = fminf(fmaxf(beta2p[0], 0.0f), 1.0f);

    // fold conv mid-tap + BN
    const float scale = bn_gamma[h] * rsqrtf(bn_var[h] + 1e-5f);
    float effw[CC];
#pragma unroll
    for (int c = 0; c < CC; ++c)
        effw[c] = 2.0f * conv_w[h * (CC * 3) + c * 3 + 1] * scale;
    const float effb = (conv_b[h] - bn_mean[h]) * scale + bn_beta[h];

    const float fw0 = fc_w[h];
    const float fw1 = fc_w[HH + h];
    const float fb0 = fc_b[0], fb0m = fb0 - 1.0f;
    const float fb1 = fc_b[1], fb1m = fb1 - 1.0f;

    const float* xb = x + (size_t)b * CC * TT;

    // chunk time range: [tw, t_end); accumulate only for t >= t_start
    const int t_start = chunk * CHT;
    const int tw      = chunk ? (t_start - WARM) : 0;
    const int t_end   = t_start + CHT;
    const int ngroups = (t_end - tw) >> 4;       // 16-step groups
    const int warm_g  = (t_start - tw) >> 4;

    // scan state (speculative zero start; contracts onto true trajectory)
    float mem1 = 0.0f, mem2_0 = 0.0f, mem2_1 = 0.0f;
    float acc0 = 0.0f, acc1 = 0.0f;
    bool s1 = false, s2_0 = false, s2_1 = false;

#define LD(c, t) (*reinterpret_cast<const float4*>(xb + (c) * TT + (t)))

    float4 buf0[CC], buf1[CC], buf2[CC], buf3[CC];
#pragma unroll
    for (int c = 0; c < CC; ++c) {
        buf0[c] = LD(c, tw);
        buf1[c] = LD(c, tw + 4);
        buf2[c] = LD(c, tw + 8);
        buf3[c] = LD(c, tw + 12);
    }

    auto step4 = [&](const float4 (&cur)[CC], float accf) {
#pragma unroll
        for (int j = 0; j < 4; ++j) {
            float feat = effb;
#pragma unroll
            for (int c = 0; c < CC; ++c)
                feat = fmaf(comp4(cur[c], j), effw[c], feat);
            const float featm = feat - 1.0f;

            mem1 = fmaf(b1, mem1, s1 ? featm : feat);
            s1 = mem1 > 1.0f;

            const float r0 = red16(s1 ? fw0 : 0.0f);
            const float r1 = red16(s1 ? fw1 : 0.0f);

            const float q0 = r0 + fb0, q0m = r0 + fb0m;
            const float q1 = r1 + fb1, q1m = r1 + fb1m;

            mem2_0 = fmaf(b2, mem2_0, s2_0 ? q0m : q0);
            s2_0 = mem2_0 > 1.0f;
            acc0 += s2_0 ? accf : 0.0f;

            mem2_1 = fmaf(b2, mem2_1, s2_1 ? q1m : q1);
            s2_1 = mem2_1 > 1.0f;
            acc1 += s2_1 ? accf : 0.0f;
        }
    };

#pragma unroll 1
    for (int g = 0; g < ngroups; ++g) {
        const int tp = (g + 1 < ngroups) ? (tw + (g + 1) * 16) : (tw + g * 16);
        const float accf = (g >= warm_g) ? 1.0f : 0.0f;

        step4(buf0, accf);
#pragma unroll
        for (int c = 0; c < CC; ++c) buf0[c] = LD(c, tp);
        step4(buf1, accf);
#pragma unroll
        for (int c = 0; c < CC; ++c) buf1[c] = LD(c, tp + 4);
        step4(buf2, accf);
#pragma unroll
        for (int c = 0; c < CC; ++c) buf2[c] = LD(c, tp + 8);
        step4(buf3, accf);
#pragma unroll
        for (int c = 0; c < CC; ++c) buf3[c] = LD(c, tp + 12);
    }
#undef LD

    if (h == 0) {
        atomicAdd(&out[(size_t)b * OO + 0], acc0);  // integer-valued -> exact, order-free
        atomicAdd(&out[(size_t)b * OO + 1], acc1);
    }
}

extern "C" void kernel_launch(void* const* d_in, const int* in_sizes, int n_in,
                              void* d_out, int out_size, void* d_ws, size_t ws_size,
                              hipStream_t stream) {
    const float* x        = (const float*)d_in[0];
    const float* conv_w   = (const float*)d_in[1];
    const float* conv_b   = (const float*)d_in[2];
    const float* bn_gamma = (const float*)d_in[3];
    const float* bn_beta  = (const float*)d_in[4];
    const float* bn_mean  = (const float*)d_in[5];
    const float* bn_var   = (const float*)d_in[6];
    const float* fc_w     = (const float*)d_in[7];
    const float* fc_b     = (const float*)d_in[8];
    const float* beta1    = (const float*)d_in[9];
    const float* beta2    = (const float*)d_in[10];
    float* out = (float*)d_out;

    hipMemsetAsync(out, 0, (size_t)out_size * sizeof(float), stream);

    dim3 grid(BB / 4, NCH);
    dim3 block(64);
    snn_chunk_kernel<<<grid, block, 0, stream>>>(
        x, conv_w, conv_b, bn_gamma, bn_beta, bn_mean, bn_var,
        fc_w, fc_b, beta1, beta2, out);
}